// Round 7
// baseline (9629.301 us; speedup 1.0000x reference)
//
#include <hip/hip_runtime.h>

#define NT 832
#define TSEQ 512

typedef float float2v __attribute__((ext_vector_type(2)));

__device__ __forceinline__ float sigmoid_(float x) { return 1.0f / (1.0f + __expf(-x)); }
__device__ __forceinline__ float tanh_(float x) { return 1.0f - 2.0f / (1.0f + __expf(2.0f * x)); }

template <int CTRL>
__device__ __forceinline__ float dppmv(float x) {
    return __int_as_float(__builtin_amdgcn_update_dpp(
        0, __float_as_int(x), CTRL, 0xF, 0xF, true));
}

// ---------------- prep kernel ----------------
// Task map (main): thread tid = p*16 + f; p = unit pair [0,50), f = k-chunk [0,16).
// Thread owns 8 gate-rows (units 2p,2p+1 x gates i,f,g,o) over k in [14f, 14f+14)
// of the padded K=224 image: l==0: [x(5); h(100); 0], l>=1: [x(100); h(100); 0].
// wflat[r*14+c], r in [0,8): r<4 -> unit 2p gate r; r>=4 -> unit 2p+1 gate r-4.
// Stored as 28 float4 per thread: wbuf[(l*28 + q)*832 + tid] = wflat[4q..4q+3].
extern "C" __global__ void prep_weights(const float* __restrict__ Wih0,
                                        const float* __restrict__ Whh0,
                                        const float* __restrict__ WihL,
                                        const float* __restrict__ WhhL,
                                        float4* __restrict__ wbuf) {
    int gid = blockIdx.x * 256 + threadIdx.x;  // 5*28*832 = 116480 total
    if (gid >= 116480) return;
    int tid = gid % 832;
    int ql = gid / 832;
    int q = ql % 28;
    int l = ql / 28;
    int p = tid / 16, f = tid % 16;
    float tmp[4] = {0.f, 0.f, 0.f, 0.f};
    if (tid < 800) {
        for (int j = 0; j < 4; ++j) {
            int e = 4 * q + j;            // 0..111
            int r = e / 14, cc = e % 14;
            int unit = 2 * p + (r >= 4 ? 1 : 0);
            int gate = r & 3;
            int row = gate * 100 + unit;
            int k = 14 * f + cc;          // 0..223
            float w = 0.f;
            if (l == 0) {
                if (k < 5) w = Wih0[row * 5 + k];
                else if (k < 105) w = Whh0[row * 100 + (k - 5)];
            } else {
                if (k < 100) w = WihL[(l - 1) * 40000 + row * 100 + k];
                else if (k < 200) w = WhhL[(l - 1) * 40000 + row * 100 + (k - 100)];
            }
            tmp[j] = w;
        }
    }
    wbuf[gid] = make_float4(tmp[0], tmp[1], tmp[2], tmp[3]);
}

// ---------------- main kernel ----------------
// One block per batch element; double-buffered xh (2x224 floats) -> 1 barrier/step.
// DPP butterfly reduces the 16 k-chunk partials within each 16-lane row (no LDS).
// LDS is deliberately padded >80KB: 1 block/CU -> 13 waves -> 4 waves/SIMD -> the
// register allocator gets a 128-VGPR budget (+AGPR headroom) for the 112 weight
// floats per thread. (R1 evidence: 89KB LDS => 128 VGPRs granted.)
template <int IN, bool FIRST, bool STORE>
__device__ void run_layer(const float4* __restrict__ wl, const float* __restrict__ bL,
                          const float* __restrict__ xsrc, float* __restrict__ hdst,
                          int b, int tid, int f, int myu, bool real,
                          float* bufs) {
    float4 wq[28];
#pragma unroll
    for (int q = 0; q < 28; ++q) wq[q] = wl[q * 832 + tid];

    float bi = 0.f, bff = 0.f, bgg = 0.f, boo = 0.f;
    if (real) {
        bi = bL[myu]; bff = bL[100 + myu]; bgg = bL[200 + myu]; boo = bL[300 + myu];
    }

    for (int i = tid; i < 448; i += NT) bufs[i] = 0.f;
    __syncthreads();
    if (FIRST) {
        if (tid < 5) bufs[tid] = xsrc[b * TSEQ * 5 + tid];
    } else {
        if (tid < 25) ((float4*)bufs)[tid] = ((const float4*)xsrc)[b * TSEQ * 25 + tid];
    }
    __syncthreads();

    float c = 0.f, hprev = 0.f;
#pragma unroll 1
    for (int t = 0; t < TSEQ; ++t) {
        float* cur = bufs + (t & 1) * 224;
        float* nxt = bufs + ((t + 1) & 1) * 224;

        // delayed global h-store (in flight during FMA; drained by end barrier)
        if (STORE) {
            if (real && f < 2 && t > 0) hdst[(b * TSEQ + t - 1) * 100 + myu] = hprev;
        }
        // prefetch next-step input
        int tn = (t + 1 < TSEQ) ? t + 1 : TSEQ - 1;
        float pfs = 0.f;
        float4 pf4 = make_float4(0.f, 0.f, 0.f, 0.f);
        if (FIRST) {
            if (tid >= 128 && tid < 133) pfs = xsrc[(b * TSEQ + tn) * 5 + (tid - 128)];
        } else {
            if (tid >= 128 && tid < 153) pf4 = ((const float4*)xsrc)[(b * TSEQ + tn) * 25 + (tid - 128)];
        }

        // read my 14-float chunk (16 distinct banks across the row -> conflict-free)
        const float2v* xp = (const float2v*)(cur + 14 * f);
        float2v xr[7];
#pragma unroll
        for (int i = 0; i < 7; ++i) xr[i] = xp[i];

        // 112 MACs as 56 v_pk_fma_f32, in TWO row-passes to halve live accumulators
        float a[8];
#pragma unroll
        for (int half = 0; half < 2; ++half) {
            float2v acc[4];
#pragma unroll
            for (int r = 0; r < 4; ++r) acc[r] = (float2v){0.f, 0.f};
#pragma unroll
            for (int cc = 0; cc < 7; ++cc) {
#pragma unroll
                for (int r = 0; r < 4; ++r) {
                    int e = (half * 4 + r) * 14 + 2 * cc;
                    float2v wp = ((e & 2) == 0) ? (float2v){wq[e >> 2].x, wq[e >> 2].y}
                                                : (float2v){wq[e >> 2].z, wq[e >> 2].w};
                    acc[r] = __builtin_elementwise_fma(wp, xr[cc], acc[r]);
                }
            }
#pragma unroll
            for (int r = 0; r < 4; ++r) a[half * 4 + r] = acc[r].x + acc[r].y;
        }

        // 4-step DPP butterfly over the 16-lane row: xor1, xor2, half_mirror, mirror
#pragma unroll
        for (int r = 0; r < 8; ++r) a[r] += dppmv<0xB1>(a[r]);   // quad_perm(1,0,3,2)
#pragma unroll
        for (int r = 0; r < 8; ++r) a[r] += dppmv<0x4E>(a[r]);   // quad_perm(2,3,0,1)
#pragma unroll
        for (int r = 0; r < 8; ++r) a[r] += dppmv<0x141>(a[r]);  // row_half_mirror
#pragma unroll
        for (int r = 0; r < 8; ++r) a[r] += dppmv<0x140>(a[r]);  // row_mirror

        // each lane handles ONE unit (parity of f): activations + state update
        bool odd = (f & 1) != 0;
        float si = (odd ? a[4] : a[0]) + bi;
        float sf = (odd ? a[5] : a[1]) + bff;
        float sg = (odd ? a[6] : a[2]) + bgg;
        float so = (odd ? a[7] : a[3]) + boo;
        float gi = sigmoid_(si);
        float gf = sigmoid_(sf);
        float gg = tanh_(sg);
        float go = sigmoid_(so);
        c = gf * c + gi * gg;
        float hv = go * tanh_(c);

        if (real && f < 2) nxt[IN + myu] = hv;   // lanes f=0,1 publish h for 2p,2p+1
        if (FIRST) {
            if (tid >= 128 && tid < 133) nxt[tid - 128] = pfs;
        } else {
            if (tid >= 128 && tid < 153) ((float4*)nxt)[tid - 128] = pf4;
        }
        hprev = hv;
        __syncthreads();
    }
    if (STORE) {
        if (real && f < 2) hdst[(b * TSEQ + TSEQ - 1) * 100 + myu] = hprev;
    }
}

extern "C" __global__ void __launch_bounds__(NT)
gesture_lstm_kernel(const float* __restrict__ x,
                    const float4* __restrict__ wbuf,
                    const float* __restrict__ b0, const float* __restrict__ bLv,
                    const float* __restrict__ gamma, const float* __restrict__ beta,
                    const float* __restrict__ rmean, const float* __restrict__ rvar,
                    const float* __restrict__ W1, const float* __restrict__ b1,
                    const float* __restrict__ W2, const float* __restrict__ b2,
                    const float* __restrict__ W3, const float* __restrict__ b3,
                    float* __restrict__ out, float* __restrict__ hseq) {
    __shared__ __align__(16) float bufs[448];   // two 224-float xh buffers
    // 84000 B: deliberately oversized so total LDS > 80KB -> 1 block/CU ->
    // 4 waves/SIMD -> 128-VGPR RA budget (see header comment).
    __shared__ __align__(16) float hw[21000];

    int tid = threadIdx.x;
    int b = blockIdx.x;
    int p = tid / 16;
    int f = tid % 16;
    int myu = 2 * p + (f & 1);
    bool real = tid < 800;

    run_layer<5,   true,  true >(wbuf + 0 * 23296, b0,         x,    hseq, b, tid, f, myu, real, bufs);
    run_layer<100, false, true >(wbuf + 1 * 23296, bLv + 0,    hseq, hseq, b, tid, f, myu, real, bufs);
    run_layer<100, false, true >(wbuf + 2 * 23296, bLv + 400,  hseq, hseq, b, tid, f, myu, real, bufs);
    run_layer<100, false, true >(wbuf + 3 * 23296, bLv + 800,  hseq, hseq, b, tid, f, myu, real, bufs);
    run_layer<100, false, false>(wbuf + 4 * 23296, bLv + 1200, hseq, hseq, b, tid, f, myu, real, bufs);

    // final h is in bufs[100..200) (t=511 wrote buffer 0, IN=100)
    // ---- head: BN (inference) -> FC1+ReLU -> FC2+ReLU -> FC3 ----
    if (tid < 100) {
        float hv = bufs[100 + tid];
        bufs[224 + tid] = (hv - rmean[tid]) * rsqrtf(rvar[tid] + 1e-5f) * gamma[tid] + beta[tid];
    }
    __syncthreads();

    for (int i = tid; i < 2500; i += NT) ((float4*)hw)[i] = ((const float4*)W1)[i];
    __syncthreads();
    if (tid < 100) {
        float acc = b1[tid];
#pragma unroll
        for (int k = 0; k < 100; ++k) acc = fmaf(hw[tid * 100 + k], bufs[224 + k], acc);
        bufs[tid] = fmaxf(acc, 0.0f);
    }
    __syncthreads();

    for (int i = tid; i < 2500; i += NT) ((float4*)hw)[i] = ((const float4*)W2)[i];
    __syncthreads();
    if (tid < 100) {
        float acc = b2[tid];
#pragma unroll
        for (int k = 0; k < 100; ++k) acc = fmaf(hw[tid * 100 + k], bufs[k], acc);
        bufs[224 + tid] = fmaxf(acc, 0.0f);
    }
    __syncthreads();

    if (tid < 3) {
        float acc = b3[tid];
#pragma unroll
        for (int k = 0; k < 100; ++k) acc = fmaf(W3[tid * 100 + k], bufs[224 + k], acc);
        out[b * 3 + tid] = acc;
    }
}

extern "C" void kernel_launch(void* const* d_in, const int* in_sizes, int n_in,
                              void* d_out, int out_size, void* d_ws, size_t ws_size,
                              hipStream_t stream) {
    const float* x     = (const float*)d_in[0];
    const float* Wih0  = (const float*)d_in[1];
    const float* Whh0  = (const float*)d_in[2];
    const float* b0    = (const float*)d_in[3];
    const float* WihL  = (const float*)d_in[4];
    const float* WhhL  = (const float*)d_in[5];
    const float* bLv   = (const float*)d_in[6];
    const float* gamma = (const float*)d_in[7];
    const float* beta  = (const float*)d_in[8];
    const float* rmean = (const float*)d_in[9];
    const float* rvar  = (const float*)d_in[10];
    const float* W1    = (const float*)d_in[11];
    const float* b1    = (const float*)d_in[12];
    const float* W2    = (const float*)d_in[13];
    const float* b2    = (const float*)d_in[14];
    const float* W3    = (const float*)d_in[15];
    const float* b3    = (const float*)d_in[16];

    float4* wbuf = (float4*)d_ws;                        // 116480 float4 = 1.864 MB
    float* hseq  = (float*)((char*)d_ws + 116480 * 16);  // 256*512*100 fp32 = 52.4 MB

    prep_weights<<<dim3(455), dim3(256), 0, stream>>>(Wih0, Whh0, WihL, WhhL, wbuf);
    gesture_lstm_kernel<<<dim3(256), dim3(NT), 0, stream>>>(
        x, wbuf, b0, bLv, gamma, beta, rmean, rvar, W1, b1, W2, b2, W3, b3,
        (float*)d_out, hseq);
}

// Round 8
// 4655.264 us; speedup vs baseline: 2.0685x; 2.0685x over previous
//
#include <hip/hip_runtime.h>

#define TSEQ 512
#define BATCH 256
#define NTR 832   // recurrence kernel threads (13 waves)

typedef float float2v __attribute__((ext_vector_type(2)));

__device__ __forceinline__ float sigmoid_(float x) { return 1.0f / (1.0f + __expf(-x)); }
__device__ __forceinline__ float tanh_(float x) { return 1.0f - 2.0f / (1.0f + __expf(2.0f * x)); }

template <int CTRL>
__device__ __forceinline__ float dppadd(float x) {
    return x + __int_as_float(__builtin_amdgcn_update_dpp(
        0, __float_as_int(x), CTRL, 0xF, 0xF, true));
}

// ============================ prep kernel ============================
// Packs three images into ws:
//  wrec  float4[5][16][NTR]: idx (l*16+kk)*NTR+tid = (Wi,Wf,Wg,Wo)[u][k], k=16f+kk,
//        u=tid>>3, f=tid&7 (zeros for k>=100, u>=100, tid>=800).
//  Wg    f32: layer0 [5][448] then layers 1..4 [100][448]; row' = 4u+g (zeros u>=100).
//  biasP f32[5][448]: bias'[l][4u+g] = b_l[g*100+u].
extern "C" __global__ void prep_all(const float* __restrict__ Wih0,
                                    const float* __restrict__ Whh0,
                                    const float* __restrict__ b0,
                                    const float* __restrict__ WihL,
                                    const float* __restrict__ WhhL,
                                    const float* __restrict__ bLv,
                                    float4* __restrict__ wrec,
                                    float* __restrict__ Wg,
                                    float* __restrict__ biasP) {
    int gid0 = blockIdx.x * 256 + threadIdx.x;
    int gstep = gridDim.x * 256;

    // wrec: 5*16*NTR float4
    for (int idx = gid0; idx < 5 * 16 * NTR; idx += gstep) {
        int l = idx / (16 * NTR);
        int r = idx % (16 * NTR);
        int kk = r / NTR;
        int tid = r % NTR;
        int u = tid >> 3, f = tid & 7;
        int k = 16 * f + kk;
        float v[4] = {0.f, 0.f, 0.f, 0.f};
        if (tid < 800 && u < 100 && k < 100) {
            for (int g = 0; g < 4; ++g) {
                int row = g * 100 + u;
                v[g] = (l == 0) ? Whh0[row * 100 + k]
                                : WhhL[(l - 1) * 40000 + row * 100 + k];
            }
        }
        wrec[idx] = make_float4(v[0], v[1], v[2], v[3]);
    }

    // Wg: 5*448 + 4*100*448 = 181440 f32
    for (int idx = gid0; idx < 181440; idx += gstep) {
        int l, k, rp;
        if (idx < 2240) { l = 0; k = idx / 448; rp = idx % 448; }
        else {
            int j = idx - 2240;
            l = 1 + j / 44800;
            int jj = j % 44800;
            k = jj / 448; rp = jj % 448;
        }
        int u = rp >> 2, g = rp & 3;
        float v = 0.f;
        if (u < 100) {
            int row = g * 100 + u;
            v = (l == 0) ? Wih0[row * 5 + k]
                         : WihL[(l - 1) * 40000 + row * 100 + k];
        }
        Wg[idx] = v;
    }

    // biasP: 5*448
    for (int idx = gid0; idx < 5 * 448; idx += gstep) {
        int l = idx / 448, rp = idx % 448;
        int u = rp >> 2, g = rp & 3;
        float v = 0.f;
        if (u < 100) v = (l == 0) ? b0[g * 100 + u] : bLv[(l - 1) * 400 + g * 100 + u];
        biasP[idx] = v;
    }
}

// ============================ GEMM kernel ============================
// G[t_local][u][b] (float4 = gates i,f,g,o) = bias + W_ih * xvec(b, t) for one chunk.
// Block: 64 rows' (16 units) x 64 cols (batch); thread (rt=tid>>4, ct=tid&15): 4 rows' x 4 cols.
template <int K, bool FIRSTL>
__global__ __launch_bounds__(256) void gemm_gx(
    const float* __restrict__ Wgl,    // [K][448] for this layer (row' = 4u+g)
    const float* __restrict__ biasPl, // [448]
    const float* __restrict__ xsrc,   // FIRSTL: x [B][512][5]; else hbuf [B][CT][100]
    float4* __restrict__ G,           // [CT][100][256]
    int t0, int CT) {
    __shared__ __align__(16) float Wt[K * 64];
    __shared__ __align__(16) float Xt[K * 64];
    int tid = threadIdx.x;
    int rb = blockIdx.x;          // 0..6
    int cb = blockIdx.y;          // 0..CT*4
    int t_local = cb >> 2;
    int b0 = (cb & 3) << 6;

    // stage W tile [K][64]
    for (int i = tid; i < K * 16; i += 256) {
        int k = i >> 4, r4 = i & 15;
        ((float4*)Wt)[k * 16 + r4] = ((const float4*)(Wgl + k * 448 + rb * 64))[r4];
    }
    // stage X tile [K][64]
    if (FIRSTL) {
        for (int i = tid; i < K * 64; i += 256) {
            int col = i & 63, j = i >> 6;
            Xt[j * 64 + col] =
                xsrc[(size_t)(b0 + col) * TSEQ * 5 + (size_t)(t0 + t_local) * 5 + j];
        }
    } else {
        for (int i = tid; i < (K / 4) * 64; i += 256) {
            int col = i & 63, j = i >> 6;
            float4 v = ((const float4*)(xsrc + (size_t)(b0 + col) * CT * 100 +
                                        (size_t)t_local * 100))[j];
            Xt[(4 * j + 0) * 64 + col] = v.x;
            Xt[(4 * j + 1) * 64 + col] = v.y;
            Xt[(4 * j + 2) * 64 + col] = v.z;
            Xt[(4 * j + 3) * 64 + col] = v.w;
        }
    }
    __syncthreads();

    int ct = tid & 15;
    int rt = tid >> 4;  // 0..15
    float4 bv = ((const float4*)biasPl)[rb * 16 + rt];
    float acc[4][4];
#pragma unroll
    for (int c = 0; c < 4; ++c) {
        acc[0][c] = bv.x; acc[1][c] = bv.y; acc[2][c] = bv.z; acc[3][c] = bv.w;
    }
#pragma unroll 4
    for (int k = 0; k < K; ++k) {
        float4 wv = ((float4*)Wt)[k * 16 + rt];
        float4 xv = ((float4*)Xt)[k * 16 + ct];
        acc[0][0] = fmaf(wv.x, xv.x, acc[0][0]);
        acc[0][1] = fmaf(wv.x, xv.y, acc[0][1]);
        acc[0][2] = fmaf(wv.x, xv.z, acc[0][2]);
        acc[0][3] = fmaf(wv.x, xv.w, acc[0][3]);
        acc[1][0] = fmaf(wv.y, xv.x, acc[1][0]);
        acc[1][1] = fmaf(wv.y, xv.y, acc[1][1]);
        acc[1][2] = fmaf(wv.y, xv.z, acc[1][2]);
        acc[1][3] = fmaf(wv.y, xv.w, acc[1][3]);
        acc[2][0] = fmaf(wv.z, xv.x, acc[2][0]);
        acc[2][1] = fmaf(wv.z, xv.y, acc[2][1]);
        acc[2][2] = fmaf(wv.z, xv.z, acc[2][2]);
        acc[2][3] = fmaf(wv.z, xv.w, acc[2][3]);
        acc[3][0] = fmaf(wv.w, xv.x, acc[3][0]);
        acc[3][1] = fmaf(wv.w, xv.y, acc[3][1]);
        acc[3][2] = fmaf(wv.w, xv.z, acc[3][2]);
        acc[3][3] = fmaf(wv.w, xv.w, acc[3][3]);
    }
    int u = rb * 16 + rt;
    if (u < 100) {
        float4* dst = G + ((size_t)t_local * 100 + u) * 256 + b0 + ct * 4;
#pragma unroll
        for (int c = 0; c < 4; ++c)
            dst[c] = make_float4(acc[0][c], acc[1][c], acc[2][c], acc[3][c]);
    }
}

// ============================ recurrence kernel ============================
// One block per batch element, one chunk of CT steps. Thread (u=tid>>3, f=tid&7)
// owns all 4 gates of unit u over k in [16f,16f+16) (zeros pad k>=100).
// h broadcast via 2x128 LDS double buffer (1 barrier/step); 8-lane DPP butterfly
// reduction; Gx (x-contribution + bias) prefetched from G; delayed h-store.
extern "C" __global__ void __launch_bounds__(NTR)
rec_step(const float4* __restrict__ wrecl,  // [16][NTR]
         const float4* __restrict__ G,      // [CT][100][256]
         float* __restrict__ hout,          // [256][CT][100]
         float* __restrict__ lastH,         // [256][100]
         float* __restrict__ cstate,        // [256][100]
         int t0, int CT) {
    __shared__ __align__(16) float hb[2][128];
    int tid = threadIdx.x;
    int b = blockIdx.x;
    int u = tid >> 3, f = tid & 7;
    bool lead = (f == 0) && (u < 100);

    float4 wq[16];
#pragma unroll
    for (int kk = 0; kk < 16; ++kk) wq[kk] = wrecl[kk * NTR + tid];

    if (tid < 128) { hb[0][tid] = 0.f; hb[1][tid] = 0.f; }
    __syncthreads();
    if (t0 > 0) { if (tid < 100) hb[0][tid] = lastH[b * 100 + tid]; }
    __syncthreads();

    float c = 0.f;
    if (t0 > 0 && lead) c = cstate[b * 100 + u];
    float hprev = 0.f;
    float4 gx = make_float4(0.f, 0.f, 0.f, 0.f);
    if (lead) gx = G[(size_t)u * 256 + b];

#pragma unroll 1
    for (int t = 0; t < CT; ++t) {
        float* cur = hb[t & 1];
        float* nxt = hb[(t + 1) & 1];

        // delayed global h-store (in flight during FMA phase)
        if (lead && t > 0) hout[((size_t)b * CT + (t - 1)) * 100 + u] = hprev;
        // prefetch Gx for t+1
        int tn = (t + 1 < CT) ? (t + 1) : t;
        float4 gxn = make_float4(0.f, 0.f, 0.f, 0.f);
        if (lead) gxn = G[((size_t)tn * 100 + u) * 256 + b];

        float4 xr0 = ((float4*)cur)[f * 4 + 0];
        float4 xr1 = ((float4*)cur)[f * 4 + 1];
        float4 xr2 = ((float4*)cur)[f * 4 + 2];
        float4 xr3 = ((float4*)cur)[f * 4 + 3];

        // 64 MACs over 4 gates as 32 v_pk_fma_f32 (2 chains per pair)
        float2v aifA = {0.f, 0.f}, aifB = {0.f, 0.f};
        float2v agoA = {0.f, 0.f}, agoB = {0.f, 0.f};
        const float x0[16] = {xr0.x, xr0.y, xr0.z, xr0.w, xr1.x, xr1.y, xr1.z, xr1.w,
                              xr2.x, xr2.y, xr2.z, xr2.w, xr3.x, xr3.y, xr3.z, xr3.w};
#pragma unroll
        for (int kk = 0; kk < 16; kk += 2) {
            float xa = x0[kk], xb = x0[kk + 1];
            aifA = __builtin_elementwise_fma((float2v){wq[kk].x, wq[kk].y},
                                             (float2v){xa, xa}, aifA);
            agoA = __builtin_elementwise_fma((float2v){wq[kk].z, wq[kk].w},
                                             (float2v){xa, xa}, agoA);
            aifB = __builtin_elementwise_fma((float2v){wq[kk + 1].x, wq[kk + 1].y},
                                             (float2v){xb, xb}, aifB);
            agoB = __builtin_elementwise_fma((float2v){wq[kk + 1].z, wq[kk + 1].w},
                                             (float2v){xb, xb}, agoB);
        }
        float ai = aifA.x + aifB.x;
        float af = aifA.y + aifB.y;
        float ag = agoA.x + agoB.x;
        float ao = agoA.y + agoB.y;

        // 3-stage butterfly over the 8-lane k-group: xor1, xor2, half-mirror
        ai = dppadd<0xB1>(ai); af = dppadd<0xB1>(af); ag = dppadd<0xB1>(ag); ao = dppadd<0xB1>(ao);
        ai = dppadd<0x4E>(ai); af = dppadd<0x4E>(af); ag = dppadd<0x4E>(ag); ao = dppadd<0x4E>(ao);
        ai = dppadd<0x141>(ai); af = dppadd<0x141>(af); ag = dppadd<0x141>(ag); ao = dppadd<0x141>(ao);

        if (lead) {
            float gi = sigmoid_(ai + gx.x);
            float gf = sigmoid_(af + gx.y);
            float gg = tanh_(ag + gx.z);
            float go = sigmoid_(ao + gx.w);
            c = gf * c + gi * gg;
            float hv = go * tanh_(c);
            nxt[u] = hv;
            hprev = hv;
        }
        gx = gxn;
        __syncthreads();
    }
    if (lead) {
        hout[((size_t)b * CT + (CT - 1)) * 100 + u] = hprev;
        lastH[b * 100 + u] = hprev;
        cstate[b * 100 + u] = c;
    }
}

// ============================ head kernel ============================
extern "C" __global__ void __launch_bounds__(128)
head_k(const float* __restrict__ lastH4,
       const float* __restrict__ gamma, const float* __restrict__ beta,
       const float* __restrict__ rmean, const float* __restrict__ rvar,
       const float* __restrict__ W1, const float* __restrict__ b1,
       const float* __restrict__ W2, const float* __restrict__ b2,
       const float* __restrict__ W3, const float* __restrict__ b3,
       float* __restrict__ out) {
    __shared__ float xa[100], ya[100];
    int b = blockIdx.x, tid = threadIdx.x;
    if (tid < 100) {
        float h = lastH4[b * 100 + tid];
        xa[tid] = (h - rmean[tid]) * rsqrtf(rvar[tid] + 1e-5f) * gamma[tid] + beta[tid];
    }
    __syncthreads();
    if (tid < 100) {
        float acc = b1[tid];
        const float4* w4 = (const float4*)(W1 + tid * 100);
#pragma unroll
        for (int j = 0; j < 25; ++j) {
            float4 w = w4[j];
            acc = fmaf(w.x, xa[4 * j + 0], acc);
            acc = fmaf(w.y, xa[4 * j + 1], acc);
            acc = fmaf(w.z, xa[4 * j + 2], acc);
            acc = fmaf(w.w, xa[4 * j + 3], acc);
        }
        ya[tid] = fmaxf(acc, 0.f);
    }
    __syncthreads();
    if (tid < 100) {
        float acc = b2[tid];
        const float4* w4 = (const float4*)(W2 + tid * 100);
#pragma unroll
        for (int j = 0; j < 25; ++j) {
            float4 w = w4[j];
            acc = fmaf(w.x, ya[4 * j + 0], acc);
            acc = fmaf(w.y, ya[4 * j + 1], acc);
            acc = fmaf(w.z, ya[4 * j + 2], acc);
            acc = fmaf(w.w, ya[4 * j + 3], acc);
        }
        xa[tid] = fmaxf(acc, 0.f);
    }
    __syncthreads();
    if (tid < 3) {
        float acc = b3[tid];
        const float4* w4 = (const float4*)(W3 + tid * 100);
#pragma unroll
        for (int j = 0; j < 25; ++j) {
            float4 w = w4[j];
            acc = fmaf(w.x, xa[4 * j + 0], acc);
            acc = fmaf(w.y, xa[4 * j + 1], acc);
            acc = fmaf(w.z, xa[4 * j + 2], acc);
            acc = fmaf(w.w, xa[4 * j + 3], acc);
        }
        out[b * 3 + tid] = acc;
    }
}

// ============================ host launch ============================
extern "C" void kernel_launch(void* const* d_in, const int* in_sizes, int n_in,
                              void* d_out, int out_size, void* d_ws, size_t ws_size,
                              hipStream_t stream) {
    const float* x     = (const float*)d_in[0];
    const float* Wih0  = (const float*)d_in[1];
    const float* Whh0  = (const float*)d_in[2];
    const float* b0    = (const float*)d_in[3];
    const float* WihL  = (const float*)d_in[4];
    const float* WhhL  = (const float*)d_in[5];
    const float* bLv   = (const float*)d_in[6];
    const float* gamma = (const float*)d_in[7];
    const float* beta  = (const float*)d_in[8];
    const float* rmean = (const float*)d_in[9];
    const float* rvar  = (const float*)d_in[10];
    const float* W1    = (const float*)d_in[11];
    const float* b1    = (const float*)d_in[12];
    const float* W2    = (const float*)d_in[13];
    const float* b2    = (const float*)d_in[14];
    const float* W3    = (const float*)d_in[15];
    const float* b3    = (const float*)d_in[16];

    char* p = (char*)d_ws;
    float4* wrec = (float4*)p;                       // 5*16*832 f4  = 1,064,960 B
    float*  Wg    = (float*)(p + 1064960);           // 181,440 f32  =   725,760 B
    float*  biasP = (float*)(p + 1790720);           // 2,240 f32    =     8,960 B
    float*  cstate= (float*)(p + 1799680);           // 5*256*100 f32=   512,000 B
    float*  lastH = (float*)(p + 2311680);           // 5*256*100 f32=   512,000 B
    const size_t base = 2824192;                     // 4K-aligned start of big bufs

    // chunk length chosen from ws_size (deterministic across calls):
    // need = base + CT*(2*102400 + 409600)
    int CT;
    if (ws_size >= base + 256ull * 614400) CT = 256;
    else if (ws_size >= base + 128ull * 614400) CT = 128;
    else CT = 64;

    float*  hbufA = (float*)(p + base);                          // [B][CT][100]
    float*  hbufB = (float*)(p + base + (size_t)CT * 102400);    // [B][CT][100]
    float4* G     = (float4*)(p + base + (size_t)CT * 204800);   // [CT][100][256]

    prep_all<<<dim3(128), dim3(256), 0, stream>>>(Wih0, Whh0, b0, WihL, WhhL, bLv,
                                                  wrec, Wg, biasP);

    int nch = TSEQ / CT;
    for (int ci = 0; ci < nch; ++ci) {
        int t0 = ci * CT;
        // layer 0 (x input, K=5)
        gemm_gx<5, true><<<dim3(7, CT * 4), dim3(256), 0, stream>>>(
            Wg, biasP, x, G, t0, CT);
        rec_step<<<dim3(BATCH), dim3(NTR), 0, stream>>>(
            wrec, G, hbufA, lastH, cstate, t0, CT);
        // layers 1..4 (h input, K=100), ping-pong A<->B
        for (int l = 1; l < 5; ++l) {
            const float* src = (l & 1) ? hbufA : hbufB;
            float* dst       = (l & 1) ? hbufB : hbufA;
            gemm_gx<100, false><<<dim3(7, CT * 4), dim3(256), 0, stream>>>(
                Wg + 2240 + (l - 1) * 44800, biasP + l * 448, src, G, t0, CT);
            rec_step<<<dim3(BATCH), dim3(NTR), 0, stream>>>(
                wrec + l * 16 * NTR, G, dst, lastH + l * 25600, cstate + l * 25600,
                t0, CT);
        }
    }

    head_k<<<dim3(BATCH), dim3(128), 0, stream>>>(
        lastH + 4 * 25600, gamma, beta, rmean, rvar, W1, b1, W2, b2, W3, b3,
        (float*)d_out);
}

// Round 9
// 4066.768 us; speedup vs baseline: 2.3678x; 1.1447x over previous
//
#include <hip/hip_runtime.h>

#define TSEQ 512
#define BATCH 256
#define NTR 832   // recurrence kernel threads (13 waves)

typedef float float2v __attribute__((ext_vector_type(2)));

__device__ __forceinline__ float sigmoid_(float x) { return 1.0f / (1.0f + __expf(-x)); }
__device__ __forceinline__ float tanh_(float x) { return 1.0f - 2.0f / (1.0f + __expf(2.0f * x)); }

template <int CTRL>
__device__ __forceinline__ float dppadd(float x) {
    return x + __int_as_float(__builtin_amdgcn_update_dpp(
        0, __float_as_int(x), CTRL, 0xF, 0xF, true));
}

// ============================ prep kernel ============================
//  wrec  float4[5][16][NTR]: idx (l*16+kk)*NTR+tid = (Wi,Wf,Wg,Wo)[u][k], k=16f+kk,
//        u=tid>>3, f=tid&7 (zeros for k>=100, u>=100, tid>=800).
//  Wg    f32: layer0 [5][448] then layers 1..4 [100][448]; row' = 4u+g (zeros u>=100).
//  biasP f32[5][448]: bias'[l][4u+g] = b_l[g*100+u].
extern "C" __global__ void prep_all(const float* __restrict__ Wih0,
                                    const float* __restrict__ Whh0,
                                    const float* __restrict__ b0,
                                    const float* __restrict__ WihL,
                                    const float* __restrict__ WhhL,
                                    const float* __restrict__ bLv,
                                    float4* __restrict__ wrec,
                                    float* __restrict__ Wg,
                                    float* __restrict__ biasP) {
    int gid0 = blockIdx.x * 256 + threadIdx.x;
    int gstep = gridDim.x * 256;

    for (int idx = gid0; idx < 5 * 16 * NTR; idx += gstep) {
        int l = idx / (16 * NTR);
        int r = idx % (16 * NTR);
        int kk = r / NTR;
        int tid = r % NTR;
        int u = tid >> 3, f = tid & 7;
        int k = 16 * f + kk;
        float v[4] = {0.f, 0.f, 0.f, 0.f};
        if (tid < 800 && u < 100 && k < 100) {
            for (int g = 0; g < 4; ++g) {
                int row = g * 100 + u;
                v[g] = (l == 0) ? Whh0[row * 100 + k]
                                : WhhL[(l - 1) * 40000 + row * 100 + k];
            }
        }
        wrec[idx] = make_float4(v[0], v[1], v[2], v[3]);
    }

    for (int idx = gid0; idx < 181440; idx += gstep) {
        int l, k, rp;
        if (idx < 2240) { l = 0; k = idx / 448; rp = idx % 448; }
        else {
            int j = idx - 2240;
            l = 1 + j / 44800;
            int jj = j % 44800;
            k = jj / 448; rp = jj % 448;
        }
        int u = rp >> 2, g = rp & 3;
        float v = 0.f;
        if (u < 100) {
            int row = g * 100 + u;
            v = (l == 0) ? Wih0[row * 5 + k]
                         : WihL[(l - 1) * 40000 + row * 100 + k];
        }
        Wg[idx] = v;
    }

    for (int idx = gid0; idx < 5 * 448; idx += gstep) {
        int l = idx / 448, rp = idx % 448;
        int u = rp >> 2, g = rp & 3;
        float v = 0.f;
        if (u < 100) v = (l == 0) ? b0[g * 100 + u] : bLv[(l - 1) * 400 + g * 100 + u];
        biasP[idx] = v;
    }
}

// ============================ GEMM kernel ============================
// G[b][t_local][u] (float4 = gates i,f,g,o) = bias + W_ih * xvec(b, t).
// Block: 64 rows' (16 units) x 64 cols (batch); thread (rt=tid&15 FAST, ct=tid>>4):
// unit u=rb*16+rt, 4 cols. rt-fast => G writes are 256B-contiguous u-segments.
template <int K, bool FIRSTL>
__global__ __launch_bounds__(256) void gemm_gx(
    const float* __restrict__ Wgl,    // [K][448] for this layer (row' = 4u+g)
    const float* __restrict__ biasPl, // [448]
    const float* __restrict__ xsrc,   // FIRSTL: x [B][512][5]; else hbuf [B][CT][100]
    float4* __restrict__ G,           // [B][CT][100] float4
    int t0, int CT) {
    __shared__ __align__(16) float Wt[K * 64];
    __shared__ __align__(16) float Xt[K * 64];
    int tid = threadIdx.x;
    int rb = blockIdx.x;          // 0..6
    int cb = blockIdx.y;          // 0..CT*4
    int t_local = cb >> 2;
    int b0 = (cb & 3) << 6;

    // stage W tile [K][64]
    for (int i = tid; i < K * 16; i += 256) {
        int k = i >> 4, r4 = i & 15;
        ((float4*)Wt)[k * 16 + r4] = ((const float4*)(Wgl + k * 448 + rb * 64))[r4];
    }
    // stage X tile [K][64]
    if (FIRSTL) {
        for (int i = tid; i < K * 64; i += 256) {
            int col = i & 63, j = i >> 6;
            Xt[j * 64 + col] =
                xsrc[(size_t)(b0 + col) * TSEQ * 5 + (size_t)(t0 + t_local) * 5 + j];
        }
    } else {
        // j fastest: 16 consecutive lanes read ~contiguous float4s of one column
        for (int i = tid; i < 25 * 64; i += 256) {
            int col = i / 25, j = i % 25;
            float4 v = ((const float4*)(xsrc + (size_t)(b0 + col) * CT * 100 +
                                        (size_t)t_local * 100))[j];
            Xt[(4 * j + 0) * 64 + col] = v.x;
            Xt[(4 * j + 1) * 64 + col] = v.y;
            Xt[(4 * j + 2) * 64 + col] = v.z;
            Xt[(4 * j + 3) * 64 + col] = v.w;
        }
    }
    __syncthreads();

    int rt = tid & 15;   // unit index within tile (FAST for coalesced G writes)
    int ct = tid >> 4;   // column group
    float4 bv = ((const float4*)biasPl)[rb * 16 + rt];
    float acc[4][4];
#pragma unroll
    for (int c = 0; c < 4; ++c) {
        acc[0][c] = bv.x; acc[1][c] = bv.y; acc[2][c] = bv.z; acc[3][c] = bv.w;
    }
#pragma unroll 4
    for (int k = 0; k < K; ++k) {
        float4 wv = ((float4*)Wt)[k * 16 + rt];
        float4 xv = ((float4*)Xt)[k * 16 + ct];
        acc[0][0] = fmaf(wv.x, xv.x, acc[0][0]);
        acc[0][1] = fmaf(wv.x, xv.y, acc[0][1]);
        acc[0][2] = fmaf(wv.x, xv.z, acc[0][2]);
        acc[0][3] = fmaf(wv.x, xv.w, acc[0][3]);
        acc[1][0] = fmaf(wv.y, xv.x, acc[1][0]);
        acc[1][1] = fmaf(wv.y, xv.y, acc[1][1]);
        acc[1][2] = fmaf(wv.y, xv.z, acc[1][2]);
        acc[1][3] = fmaf(wv.y, xv.w, acc[1][3]);
        acc[2][0] = fmaf(wv.z, xv.x, acc[2][0]);
        acc[2][1] = fmaf(wv.z, xv.y, acc[2][1]);
        acc[2][2] = fmaf(wv.z, xv.z, acc[2][2]);
        acc[2][3] = fmaf(wv.z, xv.w, acc[2][3]);
        acc[3][0] = fmaf(wv.w, xv.x, acc[3][0]);
        acc[3][1] = fmaf(wv.w, xv.y, acc[3][1]);
        acc[3][2] = fmaf(wv.w, xv.z, acc[3][2]);
        acc[3][3] = fmaf(wv.w, xv.w, acc[3][3]);
    }
    int u = rb * 16 + rt;
    if (u < 100) {
#pragma unroll
        for (int c = 0; c < 4; ++c) {
            G[((size_t)(b0 + ct * 4 + c) * CT + t_local) * 100 + u] =
                make_float4(acc[0][c], acc[1][c], acc[2][c], acc[3][c]);
        }
    }
}

// ============================ recurrence kernel ============================
// One block per batch element, one chunk of CT steps. Thread (u=tid>>3, f=tid&7)
// owns all 4 gates of unit u over k in [16f,16f+16). h broadcast via padded LDS
// double buffer (20 floats/chunk -> conflict-free banks); 8-lane DPP butterfly;
// G reads coalesced ([b][t][u], 1600B/step contiguous) with 2-deep prefetch.
extern "C" __global__ void __launch_bounds__(NTR)
rec_step(const float4* __restrict__ wrecl,  // [16][NTR]
         const float4* __restrict__ G,      // [B][CT][100]
         float* __restrict__ hout,          // [256][CT][100]
         float* __restrict__ lastH,         // [256][100]
         float* __restrict__ cstate,        // [256][100]
         int t0, int CT) {
    __shared__ __align__(16) float hb[2][160];   // 8 chunks x 20 floats, padded
    int tid = threadIdx.x;
    int b = blockIdx.x;
    int u = tid >> 3, f = tid & 7;
    bool lead = (f == 0) && (u < 100);

    float4 wq[16];
#pragma unroll
    for (int kk = 0; kk < 16; ++kk) wq[kk] = wrecl[kk * NTR + tid];

    if (tid < 160) { hb[0][tid] = 0.f; hb[1][tid] = 0.f; }
    __syncthreads();
    if (t0 > 0) {
        if (tid < 100) hb[0][(tid >> 4) * 20 + (tid & 15)] = lastH[b * 100 + tid];
    }
    __syncthreads();

    float c = 0.f;
    if (t0 > 0 && lead) c = cstate[b * 100 + u];
    float hprev = 0.f;

    const float4* Gb = G + (size_t)b * CT * 100;
    float4 gx  = make_float4(0.f, 0.f, 0.f, 0.f);
    float4 gxn = make_float4(0.f, 0.f, 0.f, 0.f);
    if (lead) {
        gx  = Gb[u];
        gxn = Gb[(size_t)(CT > 1 ? 1 : 0) * 100 + u];
    }

#pragma unroll 1
    for (int t = 0; t < CT; ++t) {
        float* cur = hb[t & 1];
        float* nxt = hb[(t + 1) & 1];

        // delayed global h-store (in flight during FMA phase)
        if (lead && t > 0) hout[((size_t)b * CT + (t - 1)) * 100 + u] = hprev;
        // prefetch G for t+2 (2-deep pipeline)
        int tn2 = (t + 2 < CT) ? (t + 2) : (CT - 1);
        float4 gx2 = make_float4(0.f, 0.f, 0.f, 0.f);
        if (lead) gx2 = Gb[(size_t)tn2 * 100 + u];

        const float4* cur4 = (const float4*)cur;
        float4 xr0 = cur4[f * 5 + 0];
        float4 xr1 = cur4[f * 5 + 1];
        float4 xr2 = cur4[f * 5 + 2];
        float4 xr3 = cur4[f * 5 + 3];

        // 64 MACs over 4 gates as 32 v_pk_fma_f32
        float2v aifA = {0.f, 0.f}, aifB = {0.f, 0.f};
        float2v agoA = {0.f, 0.f}, agoB = {0.f, 0.f};
        const float x0[16] = {xr0.x, xr0.y, xr0.z, xr0.w, xr1.x, xr1.y, xr1.z, xr1.w,
                              xr2.x, xr2.y, xr2.z, xr2.w, xr3.x, xr3.y, xr3.z, xr3.w};
#pragma unroll
        for (int kk = 0; kk < 16; kk += 2) {
            float xa = x0[kk], xb = x0[kk + 1];
            aifA = __builtin_elementwise_fma((float2v){wq[kk].x, wq[kk].y},
                                             (float2v){xa, xa}, aifA);
            agoA = __builtin_elementwise_fma((float2v){wq[kk].z, wq[kk].w},
                                             (float2v){xa, xa}, agoA);
            aifB = __builtin_elementwise_fma((float2v){wq[kk + 1].x, wq[kk + 1].y},
                                             (float2v){xb, xb}, aifB);
            agoB = __builtin_elementwise_fma((float2v){wq[kk + 1].z, wq[kk + 1].w},
                                             (float2v){xb, xb}, agoB);
        }
        float ai = aifA.x + aifB.x;
        float af = aifA.y + aifB.y;
        float ag = agoA.x + agoB.x;
        float ao = agoA.y + agoB.y;

        // 3-stage butterfly over the 8-lane k-group
        ai = dppadd<0xB1>(ai); af = dppadd<0xB1>(af); ag = dppadd<0xB1>(ag); ao = dppadd<0xB1>(ao);
        ai = dppadd<0x4E>(ai); af = dppadd<0x4E>(af); ag = dppadd<0x4E>(ag); ao = dppadd<0x4E>(ao);
        ai = dppadd<0x141>(ai); af = dppadd<0x141>(af); ag = dppadd<0x141>(ag); ao = dppadd<0x141>(ao);

        if (lead) {
            float gi = sigmoid_(ai + gx.x);
            float gf = sigmoid_(af + gx.y);
            float gg = tanh_(ag + gx.z);
            float go = sigmoid_(ao + gx.w);
            c = gf * c + gi * gg;
            float hv = go * tanh_(c);
            nxt[(u >> 4) * 20 + (u & 15)] = hv;
            hprev = hv;
        }
        gx = gxn;
        gxn = gx2;
        __syncthreads();
    }
    if (lead) {
        hout[((size_t)b * CT + (CT - 1)) * 100 + u] = hprev;
        lastH[b * 100 + u] = hprev;
        cstate[b * 100 + u] = c;
    }
}

// ============================ head kernel ============================
extern "C" __global__ void __launch_bounds__(128)
head_k(const float* __restrict__ lastH4,
       const float* __restrict__ gamma, const float* __restrict__ beta,
       const float* __restrict__ rmean, const float* __restrict__ rvar,
       const float* __restrict__ W1, const float* __restrict__ b1,
       const float* __restrict__ W2, const float* __restrict__ b2,
       const float* __restrict__ W3, const float* __restrict__ b3,
       float* __restrict__ out) {
    __shared__ float xa[100], ya[100];
    int b = blockIdx.x, tid = threadIdx.x;
    if (tid < 100) {
        float h = lastH4[b * 100 + tid];
        xa[tid] = (h - rmean[tid]) * rsqrtf(rvar[tid] + 1e-5f) * gamma[tid] + beta[tid];
    }
    __syncthreads();
    if (tid < 100) {
        float acc = b1[tid];
        const float4* w4 = (const float4*)(W1 + tid * 100);
#pragma unroll
        for (int j = 0; j < 25; ++j) {
            float4 w = w4[j];
            acc = fmaf(w.x, xa[4 * j + 0], acc);
            acc = fmaf(w.y, xa[4 * j + 1], acc);
            acc = fmaf(w.z, xa[4 * j + 2], acc);
            acc = fmaf(w.w, xa[4 * j + 3], acc);
        }
        ya[tid] = fmaxf(acc, 0.f);
    }
    __syncthreads();
    if (tid < 100) {
        float acc = b2[tid];
        const float4* w4 = (const float4*)(W2 + tid * 100);
#pragma unroll
        for (int j = 0; j < 25; ++j) {
            float4 w = w4[j];
            acc = fmaf(w.x, ya[4 * j + 0], acc);
            acc = fmaf(w.y, ya[4 * j + 1], acc);
            acc = fmaf(w.z, ya[4 * j + 2], acc);
            acc = fmaf(w.w, ya[4 * j + 3], acc);
        }
        xa[tid] = fmaxf(acc, 0.f);
    }
    __syncthreads();
    if (tid < 3) {
        float acc = b3[tid];
        const float4* w4 = (const float4*)(W3 + tid * 100);
#pragma unroll
        for (int j = 0; j < 25; ++j) {
            float4 w = w4[j];
            acc = fmaf(w.x, xa[4 * j + 0], acc);
            acc = fmaf(w.y, xa[4 * j + 1], acc);
            acc = fmaf(w.z, xa[4 * j + 2], acc);
            acc = fmaf(w.w, xa[4 * j + 3], acc);
        }
        out[b * 3 + tid] = acc;
    }
}

// ============================ host launch ============================
extern "C" void kernel_launch(void* const* d_in, const int* in_sizes, int n_in,
                              void* d_out, int out_size, void* d_ws, size_t ws_size,
                              hipStream_t stream) {
    const float* x     = (const float*)d_in[0];
    const float* Wih0  = (const float*)d_in[1];
    const float* Whh0  = (const float*)d_in[2];
    const float* b0    = (const float*)d_in[3];
    const float* WihL  = (const float*)d_in[4];
    const float* WhhL  = (const float*)d_in[5];
    const float* bLv   = (const float*)d_in[6];
    const float* gamma = (const float*)d_in[7];
    const float* beta  = (const float*)d_in[8];
    const float* rmean = (const float*)d_in[9];
    const float* rvar  = (const float*)d_in[10];
    const float* W1    = (const float*)d_in[11];
    const float* b1    = (const float*)d_in[12];
    const float* W2    = (const float*)d_in[13];
    const float* b2    = (const float*)d_in[14];
    const float* W3    = (const float*)d_in[15];
    const float* b3    = (const float*)d_in[16];

    char* p = (char*)d_ws;
    float4* wrec = (float4*)p;                       // 5*16*832 f4  = 1,064,960 B
    float*  Wg    = (float*)(p + 1064960);           // 181,440 f32  =   725,760 B
    float*  biasP = (float*)(p + 1790720);           // 2,240 f32    =     8,960 B
    float*  cstate= (float*)(p + 1799680);           // 5*256*100 f32=   512,000 B
    float*  lastH = (float*)(p + 2311680);           // 5*256*100 f32=   512,000 B
    const size_t base = 2824192;

    int CT;
    if (ws_size >= base + 256ull * 614400) CT = 256;
    else if (ws_size >= base + 128ull * 614400) CT = 128;
    else CT = 64;

    float*  hbufA = (float*)(p + base);                          // [B][CT][100]
    float*  hbufB = (float*)(p + base + (size_t)CT * 102400);    // [B][CT][100]
    float4* G     = (float4*)(p + base + (size_t)CT * 204800);   // [B][CT][100] f4

    prep_all<<<dim3(128), dim3(256), 0, stream>>>(Wih0, Whh0, b0, WihL, WhhL, bLv,
                                                  wrec, Wg, biasP);

    int nch = TSEQ / CT;
    for (int ci = 0; ci < nch; ++ci) {
        int t0 = ci * CT;
        gemm_gx<5, true><<<dim3(7, CT * 4), dim3(256), 0, stream>>>(
            Wg, biasP, x, G, t0, CT);
        rec_step<<<dim3(BATCH), dim3(NTR), 0, stream>>>(
            wrec, G, hbufA, lastH, cstate, t0, CT);
        for (int l = 1; l < 5; ++l) {
            const float* src = (l & 1) ? hbufA : hbufB;
            float* dst       = (l & 1) ? hbufB : hbufA;
            gemm_gx<100, false><<<dim3(7, CT * 4), dim3(256), 0, stream>>>(
                Wg + 2240 + (l - 1) * 44800, biasP + l * 448, src, G, t0, CT);
            rec_step<<<dim3(BATCH), dim3(NTR), 0, stream>>>(
                wrec + l * 16 * NTR, G, dst, lastH + l * 25600, cstate + l * 25600,
                t0, CT);
        }
    }

    head_k<<<dim3(BATCH), dim3(128), 0, stream>>>(
        lastH + 4 * 25600, gamma, beta, rmean, rvar, W1, b1, W2, b2, W3, b3,
        (float*)d_out);
}

// Round 10
// 3973.587 us; speedup vs baseline: 2.4233x; 1.0235x over previous
//
#include <hip/hip_runtime.h>

#define TSEQ 512
#define BATCH 256
#define NTR 832   // recurrence kernel threads (13 waves)

__device__ __forceinline__ float sigmoid_(float x) { return 1.0f / (1.0f + __expf(-x)); }
__device__ __forceinline__ float tanh_(float x) { return 1.0f - 2.0f / (1.0f + __expf(2.0f * x)); }

template <int CTRL>
__device__ __forceinline__ float dppadd(float x) {
    return x + __int_as_float(__builtin_amdgcn_update_dpp(
        0, __float_as_int(x), CTRL, 0xF, 0xF, true));
}

// ============================ prep kernel ============================
//  wrec  float4[5][16][NTR]: idx (l*16+kk)*NTR+tid = (Wi,Wf,Wg,Wo)[u][k], k=16f+kk,
//        u=tid>>3, f=tid&7 (zeros for k>=100, u>=100, tid>=800).
//  Wg    f32: layer0 [5][448] then layers 1..4 [100][448]; row' = 4u+g (zeros u>=100).
//  biasP f32[5][448]: bias'[l][4u+g] = b_l[g*100+u].
extern "C" __global__ void prep_all(const float* __restrict__ Wih0,
                                    const float* __restrict__ Whh0,
                                    const float* __restrict__ b0,
                                    const float* __restrict__ WihL,
                                    const float* __restrict__ WhhL,
                                    const float* __restrict__ bLv,
                                    float4* __restrict__ wrec,
                                    float* __restrict__ Wg,
                                    float* __restrict__ biasP) {
    int gid0 = blockIdx.x * 256 + threadIdx.x;
    int gstep = gridDim.x * 256;

    for (int idx = gid0; idx < 5 * 16 * NTR; idx += gstep) {
        int l = idx / (16 * NTR);
        int r = idx % (16 * NTR);
        int kk = r / NTR;
        int tid = r % NTR;
        int u = tid >> 3, f = tid & 7;
        int k = 16 * f + kk;
        float v[4] = {0.f, 0.f, 0.f, 0.f};
        if (tid < 800 && u < 100 && k < 100) {
            for (int g = 0; g < 4; ++g) {
                int row = g * 100 + u;
                v[g] = (l == 0) ? Whh0[row * 100 + k]
                                : WhhL[(l - 1) * 40000 + row * 100 + k];
            }
        }
        wrec[idx] = make_float4(v[0], v[1], v[2], v[3]);
    }

    for (int idx = gid0; idx < 181440; idx += gstep) {
        int l, k, rp;
        if (idx < 2240) { l = 0; k = idx / 448; rp = idx % 448; }
        else {
            int j = idx - 2240;
            l = 1 + j / 44800;
            int jj = j % 44800;
            k = jj / 448; rp = jj % 448;
        }
        int u = rp >> 2, g = rp & 3;
        float v = 0.f;
        if (u < 100) {
            int row = g * 100 + u;
            v = (l == 0) ? Wih0[row * 5 + k]
                         : WihL[(l - 1) * 40000 + row * 100 + k];
        }
        Wg[idx] = v;
    }

    for (int idx = gid0; idx < 5 * 448; idx += gstep) {
        int l = idx / 448, rp = idx % 448;
        int u = rp >> 2, g = rp & 3;
        float v = 0.f;
        if (u < 100) v = (l == 0) ? b0[g * 100 + u] : bLv[(l - 1) * 400 + g * 100 + u];
        biasP[idx] = v;
    }
}

// ============================ GEMM kernel ============================
// G[b][t_local][u] (float4 = gates i,f,g,o) = bias + W_ih * xvec(b, t).
template <int K, bool FIRSTL>
__global__ __launch_bounds__(256) void gemm_gx(
    const float* __restrict__ Wgl,    // [K][448] (row' = 4u+g)
    const float* __restrict__ biasPl, // [448]
    const float* __restrict__ xsrc,   // FIRSTL: x [B][512][5]; else hbuf [B][CT][100]
    float4* __restrict__ G,           // [B][CT][100] float4
    int t0, int CT) {
    __shared__ __align__(16) float Wt[K * 64];
    __shared__ __align__(16) float Xt[K * 64];
    int tid = threadIdx.x;
    int rb = blockIdx.x;
    int cb = blockIdx.y;
    int t_local = cb >> 2;
    int b0 = (cb & 3) << 6;

    for (int i = tid; i < K * 16; i += 256) {
        int k = i >> 4, r4 = i & 15;
        ((float4*)Wt)[k * 16 + r4] = ((const float4*)(Wgl + k * 448 + rb * 64))[r4];
    }
    if (FIRSTL) {
        for (int i = tid; i < K * 64; i += 256) {
            int col = i & 63, j = i >> 6;
            Xt[j * 64 + col] =
                xsrc[(size_t)(b0 + col) * TSEQ * 5 + (size_t)(t0 + t_local) * 5 + j];
        }
    } else {
        for (int i = tid; i < 25 * 64; i += 256) {
            int col = i / 25, j = i % 25;
            float4 v = ((const float4*)(xsrc + (size_t)(b0 + col) * CT * 100 +
                                        (size_t)t_local * 100))[j];
            Xt[(4 * j + 0) * 64 + col] = v.x;
            Xt[(4 * j + 1) * 64 + col] = v.y;
            Xt[(4 * j + 2) * 64 + col] = v.z;
            Xt[(4 * j + 3) * 64 + col] = v.w;
        }
    }
    __syncthreads();

    int rt = tid & 15;   // unit within tile (fast -> coalesced G writes)
    int ct = tid >> 4;
    float4 bv = ((const float4*)biasPl)[rb * 16 + rt];
    float acc[4][4];
#pragma unroll
    for (int c = 0; c < 4; ++c) {
        acc[0][c] = bv.x; acc[1][c] = bv.y; acc[2][c] = bv.z; acc[3][c] = bv.w;
    }
#pragma unroll 4
    for (int k = 0; k < K; ++k) {
        float4 wv = ((float4*)Wt)[k * 16 + rt];
        float4 xv = ((float4*)Xt)[k * 16 + ct];
        acc[0][0] = fmaf(wv.x, xv.x, acc[0][0]);
        acc[0][1] = fmaf(wv.x, xv.y, acc[0][1]);
        acc[0][2] = fmaf(wv.x, xv.z, acc[0][2]);
        acc[0][3] = fmaf(wv.x, xv.w, acc[0][3]);
        acc[1][0] = fmaf(wv.y, xv.x, acc[1][0]);
        acc[1][1] = fmaf(wv.y, xv.y, acc[1][1]);
        acc[1][2] = fmaf(wv.y, xv.z, acc[1][2]);
        acc[1][3] = fmaf(wv.y, xv.w, acc[1][3]);
        acc[2][0] = fmaf(wv.z, xv.x, acc[2][0]);
        acc[2][1] = fmaf(wv.z, xv.y, acc[2][1]);
        acc[2][2] = fmaf(wv.z, xv.z, acc[2][2]);
        acc[2][3] = fmaf(wv.z, xv.w, acc[2][3]);
        acc[3][0] = fmaf(wv.w, xv.x, acc[3][0]);
        acc[3][1] = fmaf(wv.w, xv.y, acc[3][1]);
        acc[3][2] = fmaf(wv.w, xv.z, acc[3][2]);
        acc[3][3] = fmaf(wv.w, xv.w, acc[3][3]);
    }
    int u = rb * 16 + rt;
    if (u < 100) {
#pragma unroll
        for (int c = 0; c < 4; ++c) {
            G[((size_t)(b0 + ct * 4 + c) * CT + t_local) * 100 + u] =
                make_float4(acc[0][c], acc[1][c], acc[2][c], acc[3][c]);
        }
    }
}

// ============================ recurrence kernel ============================
// One block per batch element. Thread (u=tid>>3, f=tid&7) owns all 4 gates of
// unit u over k in [16f,16f+16). All vmem amortized to once per 8 steps:
//  - G staged into LDS double buffer (8 steps = 800 float4, one per thread).
//  - h written to a 16-slot LDS ring, flushed coalesced every 8 steps.
// Inner loop: 64 scalar v_fma_f32 + 8-lane DPP butterfly; all lanes replicate
// activations + c (writes guarded) -> no exec-mask churn on the hot path.
extern "C" __global__ void __launch_bounds__(NTR)
rec_step(const float4* __restrict__ wrecl,  // [16][NTR]
         const float4* __restrict__ G,      // [B][CT][100] float4
         float* __restrict__ hout,          // [B][CT][100]
         float* __restrict__ lastH,         // [B][100]
         float* __restrict__ cstate,        // [B][100]
         int t0, int CT) {
    __shared__ __align__(16) float hb[2][160];      // padded h broadcast (20/chunk)
    __shared__ __align__(16) float4 Gs[2][8 * 104]; // 8-step G groups, dbl-buffered
    __shared__ float hr[16 * 112];                  // h ring (2 groups of 8)
    int tid = threadIdx.x;
    int b = blockIdx.x;
    int u = tid >> 3, f = tid & 7;
    bool lead = (f == 0) && (u < 100);
    int uc = (u < 100) ? u : 99;   // clamp for dummy lanes' Gs reads
    int ts = tid / 100, uu = tid % 100;  // staging/flush map (tid<800)

    float4 wq[16];
#pragma unroll
    for (int kk = 0; kk < 16; ++kk) wq[kk] = wrecl[kk * NTR + tid];

    const float4* Gb = G + (size_t)b * CT * 100;

    // stage group 0; init h buffers
    if (tid < 800) Gs[0][ts * 104 + uu] = Gb[ts * 100 + uu];
    if (tid < 160) { hb[0][tid] = 0.f; hb[1][tid] = 0.f; }
    __syncthreads();
    if (t0 > 0 && tid < 100) hb[0][(tid >> 4) * 20 + (tid & 15)] = lastH[b * 100 + tid];
    __syncthreads();

    float c = 0.f;
    if (t0 > 0 && u < 100) c = cstate[b * 100 + u];  // replicated in all 8 lanes
    float hv = 0.f;

#pragma unroll 1
    for (int t = 0; t < CT; ++t) {
        float* cur = hb[t & 1];
        float* nxt = hb[(t + 1) & 1];
        int g = t >> 3;

        if ((t & 7) == 0 && tid < 800) {
            // flush previous h group (coalesced, once per 8 steps)
            if (t > 0) {
                int tp = (g - 1) * 8 + ts;
                hout[((size_t)b * CT + tp) * 100 + uu] = hr[(tp & 15) * 112 + uu];
            }
            // stage next G group into the other buffer
            int tn = (g + 1) * 8 + ts;
            if (tn < CT) Gs[(g + 1) & 1][ts * 104 + uu] = Gb[(size_t)tn * 100 + uu];
        }

        // broadcast reads: gate x-contribution + h chunk
        float4 gx = Gs[g & 1][(t & 7) * 104 + uc];
        const float4* cur4 = (const float4*)cur;
        float4 x0 = cur4[f * 5 + 0];
        float4 x1 = cur4[f * 5 + 1];
        float4 x2 = cur4[f * 5 + 2];
        float4 x3 = cur4[f * 5 + 3];

        // 64 scalar FMAs, direct register operands (no repacking)
        float ai = 0.f, af = 0.f, ag = 0.f, ao = 0.f;
#define MAC_(kk, xs)                     \
    ai = fmaf(wq[kk].x, xs, ai);         \
    af = fmaf(wq[kk].y, xs, af);         \
    ag = fmaf(wq[kk].z, xs, ag);         \
    ao = fmaf(wq[kk].w, xs, ao);
        MAC_(0, x0.x)  MAC_(1, x0.y)  MAC_(2, x0.z)  MAC_(3, x0.w)
        MAC_(4, x1.x)  MAC_(5, x1.y)  MAC_(6, x1.z)  MAC_(7, x1.w)
        MAC_(8, x2.x)  MAC_(9, x2.y)  MAC_(10, x2.z) MAC_(11, x2.w)
        MAC_(12, x3.x) MAC_(13, x3.y) MAC_(14, x3.z) MAC_(15, x3.w)
#undef MAC_

        // 3-stage butterfly over the 8-lane k-group (every lane ends with the sum)
        ai = dppadd<0xB1>(ai); af = dppadd<0xB1>(af); ag = dppadd<0xB1>(ag); ao = dppadd<0xB1>(ao);
        ai = dppadd<0x4E>(ai); af = dppadd<0x4E>(af); ag = dppadd<0x4E>(ag); ao = dppadd<0x4E>(ao);
        ai = dppadd<0x141>(ai); af = dppadd<0x141>(af); ag = dppadd<0x141>(ag); ao = dppadd<0x141>(ao);

        // activations + state update replicated across all lanes (writes guarded)
        float gi = sigmoid_(ai + gx.x);
        float gf = sigmoid_(af + gx.y);
        float gg = tanh_(ag + gx.z);
        float go = sigmoid_(ao + gx.w);
        c = gf * c + gi * gg;
        hv = go * tanh_(c);
        if (lead) {
            nxt[(u >> 4) * 20 + (u & 15)] = hv;
            hr[(t & 15) * 112 + u] = hv;
        }
        __syncthreads();
    }

    // flush final h group + persist state
    if (tid < 800) {
        int tp = (CT - 8) + ts;
        hout[((size_t)b * CT + tp) * 100 + uu] = hr[(tp & 15) * 112 + uu];
    }
    if (lead) {
        lastH[b * 100 + u] = hv;
        cstate[b * 100 + u] = c;
    }
}

// ============================ head kernel ============================
extern "C" __global__ void __launch_bounds__(128)
head_k(const float* __restrict__ lastH4,
       const float* __restrict__ gamma, const float* __restrict__ beta,
       const float* __restrict__ rmean, const float* __restrict__ rvar,
       const float* __restrict__ W1, const float* __restrict__ b1,
       const float* __restrict__ W2, const float* __restrict__ b2,
       const float* __restrict__ W3, const float* __restrict__ b3,
       float* __restrict__ out) {
    __shared__ float xa[100], ya[100];
    int b = blockIdx.x, tid = threadIdx.x;
    if (tid < 100) {
        float h = lastH4[b * 100 + tid];
        xa[tid] = (h - rmean[tid]) * rsqrtf(rvar[tid] + 1e-5f) * gamma[tid] + beta[tid];
    }
    __syncthreads();
    if (tid < 100) {
        float acc = b1[tid];
        const float4* w4 = (const float4*)(W1 + tid * 100);
#pragma unroll
        for (int j = 0; j < 25; ++j) {
            float4 w = w4[j];
            acc = fmaf(w.x, xa[4 * j + 0], acc);
            acc = fmaf(w.y, xa[4 * j + 1], acc);
            acc = fmaf(w.z, xa[4 * j + 2], acc);
            acc = fmaf(w.w, xa[4 * j + 3], acc);
        }
        ya[tid] = fmaxf(acc, 0.f);
    }
    __syncthreads();
    if (tid < 100) {
        float acc = b2[tid];
        const float4* w4 = (const float4*)(W2 + tid * 100);
#pragma unroll
        for (int j = 0; j < 25; ++j) {
            float4 w = w4[j];
            acc = fmaf(w.x, ya[4 * j + 0], acc);
            acc = fmaf(w.y, ya[4 * j + 1], acc);
            acc = fmaf(w.z, ya[4 * j + 2], acc);
            acc = fmaf(w.w, ya[4 * j + 3], acc);
        }
        xa[tid] = fmaxf(acc, 0.f);
    }
    __syncthreads();
    if (tid < 3) {
        float acc = b3[tid];
        const float4* w4 = (const float4*)(W3 + tid * 100);
#pragma unroll
        for (int j = 0; j < 25; ++j) {
            float4 w = w4[j];
            acc = fmaf(w.x, xa[4 * j + 0], acc);
            acc = fmaf(w.y, xa[4 * j + 1], acc);
            acc = fmaf(w.z, xa[4 * j + 2], acc);
            acc = fmaf(w.w, xa[4 * j + 3], acc);
        }
        out[b * 3 + tid] = acc;
    }
}

// ============================ host launch ============================
extern "C" void kernel_launch(void* const* d_in, const int* in_sizes, int n_in,
                              void* d_out, int out_size, void* d_ws, size_t ws_size,
                              hipStream_t stream) {
    const float* x     = (const float*)d_in[0];
    const float* Wih0  = (const float*)d_in[1];
    const float* Whh0  = (const float*)d_in[2];
    const float* b0    = (const float*)d_in[3];
    const float* WihL  = (const float*)d_in[4];
    const float* WhhL  = (const float*)d_in[5];
    const float* bLv   = (const float*)d_in[6];
    const float* gamma = (const float*)d_in[7];
    const float* beta  = (const float*)d_in[8];
    const float* rmean = (const float*)d_in[9];
    const float* rvar  = (const float*)d_in[10];
    const float* W1    = (const float*)d_in[11];
    const float* b1    = (const float*)d_in[12];
    const float* W2    = (const float*)d_in[13];
    const float* b2    = (const float*)d_in[14];
    const float* W3    = (const float*)d_in[15];
    const float* b3    = (const float*)d_in[16];

    char* p = (char*)d_ws;
    float4* wrec = (float4*)p;                       // 5*16*832 f4  = 1,064,960 B
    float*  Wg    = (float*)(p + 1064960);           // 181,440 f32
    float*  biasP = (float*)(p + 1790720);           // 2,240 f32
    float*  cstate= (float*)(p + 1799680);           // 5*256*100 f32
    float*  lastH = (float*)(p + 2311680);           // 5*256*100 f32
    const size_t base = 2824192;

    int CT;
    if (ws_size >= base + 256ull * 614400) CT = 256;
    else if (ws_size >= base + 128ull * 614400) CT = 128;
    else CT = 64;

    float*  hbufA = (float*)(p + base);                          // [B][CT][100]
    float*  hbufB = (float*)(p + base + (size_t)CT * 102400);    // [B][CT][100]
    float4* G     = (float4*)(p + base + (size_t)CT * 204800);   // [B][CT][100] f4

    prep_all<<<dim3(128), dim3(256), 0, stream>>>(Wih0, Whh0, b0, WihL, WhhL, bLv,
                                                  wrec, Wg, biasP);

    int nch = TSEQ / CT;
    for (int ci = 0; ci < nch; ++ci) {
        int t0 = ci * CT;
        gemm_gx<5, true><<<dim3(7, CT * 4), dim3(256), 0, stream>>>(
            Wg, biasP, x, G, t0, CT);
        rec_step<<<dim3(BATCH), dim3(NTR), 0, stream>>>(
            wrec, G, hbufA, lastH, cstate, t0, CT);
        for (int l = 1; l < 5; ++l) {
            const float* src = (l & 1) ? hbufA : hbufB;
            float* dst       = (l & 1) ? hbufB : hbufA;
            gemm_gx<100, false><<<dim3(7, CT * 4), dim3(256), 0, stream>>>(
                Wg + 2240 + (l - 1) * 44800, biasP + l * 448, src, G, t0, CT);
            rec_step<<<dim3(BATCH), dim3(NTR), 0, stream>>>(
                wrec + l * 16 * NTR, G, dst, lastH + l * 25600, cstate + l * 25600,
                t0, CT);
        }
    }

    head_k<<<dim3(BATCH), dim3(128), 0, stream>>>(
        lastH + 4 * 25600, gamma, beta, rmean, rvar, W1, b1, W2, b2, W3, b3,
        (float*)d_out);
}